// Round 3
// baseline (3058.322 us; speedup 1.0000x reference)
//
#include <hip/hip_runtime.h>
#include <cstddef>
#include <cstdint>

#define T_LEN 1024
#define B_N   64
#define H_N   128
#define G_N   512     // 4*H
#define HD1_N 256
#define HD2_N 64
#define EPS_F 1e-5f

// bf16 pack/unpack (RNE; inputs finite)
__device__ __forceinline__ unsigned short f2bf(float f) {
    unsigned int u = __float_as_uint(f);
    return (unsigned short)((u + 0x7FFFu + ((u >> 16) & 1u)) >> 16);
}
__device__ __forceinline__ float bf2f(unsigned short h) {
    return __uint_as_float(((unsigned int)h) << 16);
}

// ---------------------------------------------------------------------------
// GEMM: xp[dir][t][b][512] = A(m) . W_dir[j][:] + (b_ih+b_hh)[j], stored bf16.
// A is either x ([B][T][K], m=t*64+b) or l0out ([M][K] row-major).
// grid: (512, 8), block 256. Tile 128x128, micro 8x8, BK=8.
// ---------------------------------------------------------------------------
__global__ __launch_bounds__(256, 2)
void gemm_xp(const float* __restrict__ A,
             const float* __restrict__ w0, const float* __restrict__ w1,
             const float* __restrict__ bi0, const float* __restrict__ bh0,
             const float* __restrict__ bi1, const float* __restrict__ bh1,
             unsigned short* __restrict__ xp, int K, int a_is_x)
{
    const int mt = blockIdx.x, nt = blockIdx.y;
    const int m0 = mt * 128, n0 = nt * 128;
    const int dir = n0 >> 9;
    const int jj0 = n0 & 511;
    const float* __restrict__ W  = dir ? w1 : w0;
    const float* __restrict__ bi = dir ? bi1 : bi0;
    const float* __restrict__ bh = dir ? bh1 : bh0;
    const int tid = threadIdx.x;
    const int lr = tid >> 1;
    const int lc = (tid & 1) * 4;

    __shared__ __align__(16) float As[8][132];
    __shared__ __align__(16) float Bs[8][132];

    size_t arow;
    {
        int am = m0 + lr;
        if (a_is_x) { int t = am >> 6, b = am & 63; arow = ((size_t)b * T_LEN + t) * (size_t)K; }
        else        { arow = (size_t)am * (size_t)K; }
    }
    const size_t brow = (size_t)(jj0 + lr) * (size_t)K;

    float acc[8][8];
#pragma unroll
    for (int i = 0; i < 8; ++i)
#pragma unroll
        for (int j = 0; j < 8; ++j) acc[i][j] = 0.f;

    const int ty = tid >> 4, tx = tid & 15;

    for (int k0 = 0; k0 < K; k0 += 8) {
        float4 av = *(const float4*)(A + arow + k0 + lc);
        float4 bv = *(const float4*)(W + brow + k0 + lc);
        __syncthreads();
        As[lc+0][lr] = av.x; As[lc+1][lr] = av.y; As[lc+2][lr] = av.z; As[lc+3][lr] = av.w;
        Bs[lc+0][lr] = bv.x; Bs[lc+1][lr] = bv.y; Bs[lc+2][lr] = bv.z; Bs[lc+3][lr] = bv.w;
        __syncthreads();
#pragma unroll
        for (int kk = 0; kk < 8; ++kk) {
            float a[8], bb[8];
            float4 t0 = *(const float4*)&As[kk][ty*8];
            float4 t1 = *(const float4*)&As[kk][ty*8+4];
            a[0]=t0.x; a[1]=t0.y; a[2]=t0.z; a[3]=t0.w;
            a[4]=t1.x; a[5]=t1.y; a[6]=t1.z; a[7]=t1.w;
            float4 u0 = *(const float4*)&Bs[kk][tx*8];
            float4 u1 = *(const float4*)&Bs[kk][tx*8+4];
            bb[0]=u0.x; bb[1]=u0.y; bb[2]=u0.z; bb[3]=u0.w;
            bb[4]=u1.x; bb[5]=u1.y; bb[6]=u1.z; bb[7]=u1.w;
#pragma unroll
            for (int i = 0; i < 8; ++i)
#pragma unroll
                for (int j = 0; j < 8; ++j)
                    acc[i][j] += a[i] * bb[j];
        }
    }

    float bias[8];
#pragma unroll
    for (int j = 0; j < 8; ++j) {
        int jj = jj0 + tx*8 + j;
        bias[j] = bi[jj] + bh[jj];
    }
    const size_t outbase = (size_t)dir * (size_t)T_LEN * B_N * G_N;
#pragma unroll
    for (int i = 0; i < 8; ++i) {
        int m = m0 + ty*8 + i;
        unsigned int pk[4];
#pragma unroll
        for (int j = 0; j < 4; ++j) {
            unsigned short lo = f2bf(acc[i][2*j]   + bias[2*j]);
            unsigned short hi = f2bf(acc[i][2*j+1] + bias[2*j+1]);
            pk[j] = (unsigned int)lo | ((unsigned int)hi << 16);
        }
        unsigned short* op = xp + outbase + (size_t)m * G_N + jj0 + tx*8;
        *(uint4*)(op) = make_uint4(pk[0], pk[1], pk[2], pk[3]);
    }
}

// ---------------------------------------------------------------------------
// Persistent per-(dir,batch) LSTM scan. grid 128 (dir*64+b), block 512.
// thread = (c = tid&127 column, rp = tid>>7 k-quarter). w_hh rows for gates
// {c, 128+c, 256+c, 384+c}, cols [rp*32, rp*32+32) live in 128 VGPRs.
// ---------------------------------------------------------------------------
__global__ __launch_bounds__(512, 2)
void lstm_scan(const unsigned short* __restrict__ xp,
               const float* __restrict__ whh_f, const float* __restrict__ whh_r,
               float* __restrict__ hout)
{
    const int tid = threadIdx.x;
    const int c   = tid & 127;
    const int rp  = tid >> 7;
    const int dir = blockIdx.x >> 6;
    const int b   = blockIdx.x & 63;
    const float* __restrict__ whh = dir ? whh_r : whh_f;
    const unsigned short* __restrict__ xpd =
        xp + (size_t)dir * T_LEN * B_N * G_N + (size_t)b * G_N;

    float w[4][32];
#pragma unroll
    for (int g = 0; g < 4; ++g) {
        const float* wr = whh + (size_t)(g * H_N + c) * H_N + rp * 32;
#pragma unroll
        for (int kk = 0; kk < 32; kk += 4) {
            float4 v = *(const float4*)(wr + kk);
            w[g][kk]=v.x; w[g][kk+1]=v.y; w[g][kk+2]=v.z; w[g][kk+3]=v.w;
        }
    }

    __shared__ __align__(16) float h_sh[128];
    __shared__ float part[4][4][128];   // [gate][rp][col]
    __shared__ float gates_sh[512];

    if (tid < 128) h_sh[tid] = 0.f;
    float cst = 0.f;                    // cell state, valid for tid<128
    __syncthreads();

    float xpv = bf2f(xpd[(size_t)(dir ? (T_LEN-1) : 0) * B_N * G_N + tid]);

    for (int step = 0; step < T_LEN; ++step) {
        const int t = dir ? (T_LEN - 1 - step) : step;
        const int stepn = (step + 1 < T_LEN) ? step + 1 : step;
        const int tn = dir ? (T_LEN - 1 - stepn) : stepn;
        float xpn = bf2f(xpd[(size_t)tn * B_N * G_N + tid]);  // prefetch next

        float a0=0.f, a1=0.f, a2=0.f, a3=0.f;
#pragma unroll
        for (int kk = 0; kk < 32; kk += 4) {
            float4 h4 = *(const float4*)&h_sh[rp*32 + kk];
            a0 += w[0][kk+0]*h4.x + w[0][kk+1]*h4.y + w[0][kk+2]*h4.z + w[0][kk+3]*h4.w;
            a1 += w[1][kk+0]*h4.x + w[1][kk+1]*h4.y + w[1][kk+2]*h4.z + w[1][kk+3]*h4.w;
            a2 += w[2][kk+0]*h4.x + w[2][kk+1]*h4.y + w[2][kk+2]*h4.z + w[2][kk+3]*h4.w;
            a3 += w[3][kk+0]*h4.x + w[3][kk+1]*h4.y + w[3][kk+2]*h4.z + w[3][kk+3]*h4.w;
        }
        part[0][rp][c]=a0; part[1][rp][c]=a1; part[2][rp][c]=a2; part[3][rp][c]=a3;
        __syncthreads();
        {
            float s = xpv + part[rp][0][c] + part[rp][1][c] + part[rp][2][c] + part[rp][3][c];
            float v;
            if (rp == 2) { float e = __expf(2.f*s); v = 1.f - 2.f/(e+1.f); }   // tanh(g)
            else         { v = 1.f / (1.f + __expf(-s)); }                     // sigmoid
            gates_sh[tid] = v;
        }
        __syncthreads();
        if (tid < 128) {
            float iv = gates_sh[tid];
            float fv = gates_sh[128+tid];
            float gv = gates_sh[256+tid];
            float ov = gates_sh[384+tid];
            cst = fv*cst + iv*gv;
            float e = __expf(2.f*cst);
            float th = 1.f - 2.f/(e+1.f);
            float hv = ov*th;
            h_sh[tid] = hv;
            hout[((size_t)t * B_N + b) * HD1_N + dir * H_N + tid] = hv;
        }
        xpv = xpn;
        __syncthreads();
    }
}

// ---------------------------------------------------------------------------
// Head: h2 = BN2(tanh(BN1(l1out) @ lin_w.T + lin_b)). BN1 folded into A-load.
// grid 512, block 256. Tile 128x64, micro 8x4, BK=8.
// ---------------------------------------------------------------------------
__global__ __launch_bounds__(256, 2)
void head_gemm(const float* __restrict__ A,
               const float* __restrict__ lin_w, const float* __restrict__ lin_b,
               const float* __restrict__ g1, const float* __restrict__ b1v,
               const float* __restrict__ m1, const float* __restrict__ v1,
               const float* __restrict__ g2, const float* __restrict__ b2v,
               const float* __restrict__ m2, const float* __restrict__ v2,
               float* __restrict__ h2out)
{
    const int m0 = blockIdx.x * 128;
    const int tid = threadIdx.x;
    __shared__ __align__(16) float As[8][132];
    __shared__ __align__(16) float Bs[8][68];
    const int lr  = tid >> 1, lc = (tid & 1) * 4;
    const int lrB = tid & 63, kcB = (tid >> 6) * 2;
    const int ty = tid >> 4, tx = tid & 15;

    float acc[8][4];
#pragma unroll
    for (int i = 0; i < 8; ++i)
#pragma unroll
        for (int j = 0; j < 4; ++j) acc[i][j] = 0.f;

    const size_t arow = (size_t)(m0 + lr) * HD1_N;
    for (int k0 = 0; k0 < HD1_N; k0 += 8) {
        float4 av = *(const float4*)(A + arow + k0 + lc);
        float4 gm = *(const float4*)(m1 + k0 + lc);
        float4 gg = *(const float4*)(g1 + k0 + lc);
        float4 gv = *(const float4*)(v1 + k0 + lc);
        float2 bv = *(const float2*)(lin_w + (size_t)lrB * HD1_N + k0 + kcB);
        __syncthreads();
        As[lc+0][lr] = (av.x - gm.x) * (gg.x * rsqrtf(gv.x + EPS_F));
        As[lc+1][lr] = (av.y - gm.y) * (gg.y * rsqrtf(gv.y + EPS_F));
        As[lc+2][lr] = (av.z - gm.z) * (gg.z * rsqrtf(gv.z + EPS_F));
        As[lc+3][lr] = (av.w - gm.w) * (gg.w * rsqrtf(gv.w + EPS_F));
        Bs[kcB][lrB]   = bv.x;
        Bs[kcB+1][lrB] = bv.y;
        __syncthreads();
#pragma unroll
        for (int kk = 0; kk < 8; ++kk) {
            float a[8], bb[4];
            float4 t0 = *(const float4*)&As[kk][ty*8];
            float4 t1 = *(const float4*)&As[kk][ty*8+4];
            a[0]=t0.x; a[1]=t0.y; a[2]=t0.z; a[3]=t0.w;
            a[4]=t1.x; a[5]=t1.y; a[6]=t1.z; a[7]=t1.w;
            float4 u0 = *(const float4*)&Bs[kk][tx*4];
            bb[0]=u0.x; bb[1]=u0.y; bb[2]=u0.z; bb[3]=u0.w;
#pragma unroll
            for (int i = 0; i < 8; ++i)
#pragma unroll
                for (int j = 0; j < 4; ++j)
                    acc[i][j] += a[i] * bb[j];
        }
    }

#pragma unroll
    for (int j = 0; j < 4; ++j) {
        int n = tx*4 + j;
        float s2 = g2[n] * rsqrtf(v2[n] + EPS_F);
        float t2 = b2v[n] - m2[n] * s2;
        float lb = lin_b[n];
#pragma unroll
        for (int i = 0; i < 8; ++i) {
            float y = acc[i][j] + lb;
            acc[i][j] = tanhf(y) * s2 + t2;
        }
    }
#pragma unroll
    for (int i = 0; i < 8; ++i) {
        int m = m0 + ty*8 + i;
        float4 o;
        o.x = acc[i][0]; o.y = acc[i][1]; o.z = acc[i][2]; o.w = acc[i][3];
        *(float4*)(h2out + (size_t)m * HD2_N + tx*4) = o;
    }
}

// ---------------------------------------------------------------------------
// hw[m][k] = h2[m][:] . out_w[k][4:] + out_b[k]   (k = 0,1)
// ---------------------------------------------------------------------------
__global__ __launch_bounds__(256)
void hw_kernel(const float* __restrict__ h2, const float* __restrict__ out_w,
               const float* __restrict__ out_b, float* __restrict__ hw)
{
    int m = blockIdx.x * blockDim.x + threadIdx.x;
    const float* w0 = out_w + 4;
    const float* w1 = out_w + 68 + 4;
    float a0 = out_b[0], a1 = out_b[1];
    const float* row = h2 + (size_t)m * HD2_N;
#pragma unroll
    for (int j = 0; j < 64; j += 4) {
        float4 hv = *(const float4*)(row + j);
        a0 += hv.x*w0[j] + hv.y*w0[j+1] + hv.z*w0[j+2] + hv.w*w0[j+3];
        a1 += hv.x*w1[j] + hv.y*w1[j+1] + hv.z*w1[j+2] + hv.w*w1[j+3];
    }
    *(float2*)(hw + (size_t)m * 2) = make_float2(a0, a1);
}

// ---------------------------------------------------------------------------
// Serial class-context scan: lane = batch, 8-deep prefetch on hw.
// out row = b*T + t (batch-major flatten).
// ---------------------------------------------------------------------------
__global__ void ctx_kernel(const float* __restrict__ hw,
                           const float* __restrict__ out_w,
                           float* __restrict__ out)
{
    int b = threadIdx.x;  // 64 threads
    float w00=out_w[0],  w01=out_w[1],  w02=out_w[2],  w03=out_w[3];
    float w10=out_w[68], w11=out_w[69], w12=out_w[70], w13=out_w[71];
    float c0=0.f, c1=0.f, c2=0.f, c3=0.f;
    float2 buf[8];
#pragma unroll
    for (int u = 0; u < 8; ++u)
        buf[u] = *(const float2*)&hw[((size_t)u * B_N + b) * 2];
    for (int tb = 0; tb < T_LEN; tb += 8) {
#pragma unroll
        for (int u = 0; u < 8; ++u) {
            int t = tb + u;
            float2 hv = buf[u];
            int tnext = t + 8;
            if (tnext < T_LEN)
                buf[u] = *(const float2*)&hw[((size_t)tnext * B_N + b) * 2];
            float l0 = hv.x + c0*w00 + c1*w01 + c2*w02 + c3*w03;
            float l1 = hv.y + c0*w10 + c1*w11 + c2*w12 + c3*w13;
            float mx = fmaxf(l0, l1);
            float lse = mx + __logf(__expf(l0 - mx) + __expf(l1 - mx));
            l0 -= lse; l1 -= lse;
            c0 = c2; c1 = c3; c2 = l0; c3 = l1;
            *(float2*)&out[((size_t)b * T_LEN + t) * 2] = make_float2(l0, l1);
        }
    }
}

// ---------------------------------------------------------------------------
// Workspace budget (must stay small — unknown ws_size; R1's 420 MB aborted):
//   xp    : bf16, 2*T*B*512 = 67,108,864 elem = 128 MiB   [offset 0]
//   l0out : f32,  T*B*256   = 16,777,216 elem =  64 MiB   [offset 128 MiB]
//   l1out : aliases l0out (l0out dead once gemm-L1 consumed it)
//   h2    : f32, 4,194,304 elem — aliases xp (xp dead after scan-L1)
//   hw    : f32,   131,072 elem — aliases xp + h2
//   total footprint = 192 MiB
// ---------------------------------------------------------------------------
extern "C" void kernel_launch(void* const* d_in, const int* in_sizes, int n_in,
                              void* d_out, int out_size, void* d_ws, size_t ws_size,
                              hipStream_t stream)
{
    (void)in_sizes; (void)n_in; (void)out_size; (void)ws_size;
    const float* x        = (const float*)d_in[0];
    const float* w_ih_l0  = (const float*)d_in[1];
    const float* w_hh_l0  = (const float*)d_in[2];
    const float* b_ih_l0  = (const float*)d_in[3];
    const float* b_hh_l0  = (const float*)d_in[4];
    const float* w_ih_l0r = (const float*)d_in[5];
    const float* w_hh_l0r = (const float*)d_in[6];
    const float* b_ih_l0r = (const float*)d_in[7];
    const float* b_hh_l0r = (const float*)d_in[8];
    const float* w_ih_l1  = (const float*)d_in[9];
    const float* w_hh_l1  = (const float*)d_in[10];
    const float* b_ih_l1  = (const float*)d_in[11];
    const float* b_hh_l1  = (const float*)d_in[12];
    const float* w_ih_l1r = (const float*)d_in[13];
    const float* w_hh_l1r = (const float*)d_in[14];
    const float* b_ih_l1r = (const float*)d_in[15];
    const float* b_hh_l1r = (const float*)d_in[16];
    const float* bn1_g = (const float*)d_in[17];
    const float* bn1_b = (const float*)d_in[18];
    const float* bn1_m = (const float*)d_in[19];
    const float* bn1_v = (const float*)d_in[20];
    const float* lin_w = (const float*)d_in[21];
    const float* lin_b = (const float*)d_in[22];
    const float* bn2_g = (const float*)d_in[23];
    const float* bn2_b = (const float*)d_in[24];
    const float* bn2_m = (const float*)d_in[25];
    const float* bn2_v = (const float*)d_in[26];
    const float* out_w = (const float*)d_in[27];
    const float* out_b = (const float*)d_in[28];
    float* out = (float*)d_out;

    unsigned short* xp = (unsigned short*)d_ws;             // 67,108,864 bf16
    float* l0out = (float*)((char*)d_ws + 134217728);       // 16,777,216 f32
    float* l1out = l0out;                                   // alias (safe)
    float* h2    = (float*)d_ws;                            // alias xp (safe)
    float* hw    = h2 + 4194304;                            // alias xp (safe)

    dim3 gg(512, 8);
    gemm_xp<<<gg, 256, 0, stream>>>(x, w_ih_l0, w_ih_l0r, b_ih_l0, b_hh_l0,
                                    b_ih_l0r, b_hh_l0r, xp, 400, 1);
    lstm_scan<<<128, 512, 0, stream>>>(xp, w_hh_l0, w_hh_l0r, l0out);
    gemm_xp<<<gg, 256, 0, stream>>>(l0out, w_ih_l1, w_ih_l1r, b_ih_l1, b_hh_l1,
                                    b_ih_l1r, b_hh_l1r, xp, 256, 0);
    lstm_scan<<<128, 512, 0, stream>>>(xp, w_hh_l1, w_hh_l1r, l1out);
    head_gemm<<<512, 256, 0, stream>>>(l1out, lin_w, lin_b,
                                       bn1_g, bn1_b, bn1_m, bn1_v,
                                       bn2_g, bn2_b, bn2_m, bn2_v, h2);
    hw_kernel<<<256, 256, 0, stream>>>(h2, out_w, out_b, hw);
    ctx_kernel<<<1, 64, 0, stream>>>(hw, out_w, out);
}